// Round 12
// baseline (310.304 us; speedup 1.0000x reference)
//
#include <hip/hip_runtime.h>

#define B_ 4
#define N_ 2048
#define M_ 2048
#define M2_ 4096
#define D_ 128
#define K_ 512
#define NBLK 5376

__constant__ float LIGQ[10]  = {0.f,-0.3f,-0.4f,-0.1f,0.1f,-0.2f,-0.1f,-0.1f,-0.1f,0.1f};
__constant__ float PROTQ[4]  = {0.f,-0.3f,-0.4f,-0.2f};

// ---------------------------------------------------------------- zero: mins + counters
__global__ __launch_bounds__(256) void k_zero(unsigned* rowmin, unsigned* colmin, unsigned* cnts) {
    int i = blockIdx.x * 256 + threadIdx.x;
    rowmin[i] = 0x7F800000u;
    colmin[i] = 0x7F800000u;
    if (i < 2) cnts[i] = 0u;
}

// ---------------------------------------------------------------- all-in-one
// vb<2048 cross | <3072 vq-score | <4096 yy | <5120 chamfer | else vqep(spin)
__global__ __launch_bounds__(256) void k_all(const float* __restrict__ x,
                                             const float* __restrict__ yg,
                                             const float* __restrict__ pg,
                                             const float* __restrict__ enc,
                                             const float* __restrict__ emb,
                                             const float* __restrict__ Ts,
                                             const float* __restrict__ Tc,
                                             const float* __restrict__ sf,
                                             const float* __restrict__ pf,
                                             unsigned long long* vqbPart,
                                             unsigned* rowmin, unsigned* colmin,
                                             double* pT, double* pE, double* pV,
                                             double* pyy, double* pvq,
                                             unsigned* cnts, float* out) {
    __shared__ __align__(16) char smem[16640];
    __shared__ unsigned lastFlag;
    int vb = blockIdx.x;
    int tid = threadIdx.x;

    if (vb < 2048) {
        // ---------------- cross: tpl_cross + elec + vdw (charges inline)
        float4* lyq = (float4*)smem;
        float4* lpq = (float4*)(smem + 4096);
        double* wred = (double*)(smem + 8192);
        int it = vb >> 6, jt = vb & 63;
        int i0 = it * 64, j0 = jt * 64;
        {
            int b = tid >> 6, r = tid & 63;
            size_t yi = (size_t)(b * M_ + i0 + r);
            const float* yp = &yg[yi * 3];
            const float* sfr = sf + yi * D_;
            float4 s0 = *(const float4*)sfr;
            float4 s1 = *(const float4*)(sfr + 4);
            float2 s2 = *(const float2*)(sfr + 8);
            float best = s0.x; int bi = 0;
            if (s0.y > best) { best = s0.y; bi = 1; }
            if (s0.z > best) { best = s0.z; bi = 2; }
            if (s0.w > best) { best = s0.w; bi = 3; }
            if (s1.x > best) { best = s1.x; bi = 4; }
            if (s1.y > best) { best = s1.y; bi = 5; }
            if (s1.z > best) { best = s1.z; bi = 6; }
            if (s1.w > best) { best = s1.w; bi = 7; }
            if (s2.x > best) { best = s2.x; bi = 8; }
            if (s2.y > best) { best = s2.y; bi = 9; }
            lyq[tid] = make_float4(yp[0], yp[1], yp[2], LIGQ[bi]);
            size_t pi = (size_t)(b * M2_ + j0 + r);
            const float* pp = &pg[pi * 3];
            float4 p0 = *(const float4*)(pf + pi * D_);
            float pb = p0.x; int pbi = 0;
            if (p0.y > pb) { pb = p0.y; pbi = 1; }
            if (p0.z > pb) { pb = p0.z; pbi = 2; }
            if (p0.w > pb) { pb = p0.w; pbi = 3; }
            lpq[tid] = make_float4(pp[0], pp[1], pp[2], PROTQ[pbi]);
        }
        __syncthreads();

        int tj = tid & 15, ti = tid >> 4;
        float tcs[4][4];
#pragma unroll
        for (int a = 0; a < 4; a++) {
            const float* tr = &Tc[((size_t)(i0 + ti * 4 + a)) * M2_ + j0 + tj];
#pragma unroll
            for (int jj = 0; jj < 4; jj++) tcs[a][jj] = tr[jj * 16];
        }
        float s_tpl = 0.f, s_elec = 0.f, s_vdw = 0.f;
#pragma unroll
        for (int b = 0; b < B_; b++) {
            float4 row[4], col[4];
#pragma unroll
            for (int a = 0; a < 4; a++) row[a] = lyq[b * 64 + ti * 4 + a];
#pragma unroll
            for (int jj = 0; jj < 4; jj++) col[jj] = lpq[b * 64 + jj * 16 + tj];
#pragma unroll
            for (int jj = 0; jj < 4; jj++)
#pragma unroll
                for (int a = 0; a < 4; a++) {
                    float dx = row[a].x - col[jj].x;
                    float dy = row[a].y - col[jj].y;
                    float dz = row[a].z - col[jj].z;
                    float d2 = fmaf(dz, dz, fmaf(dy, dy, dx * dx));
                    float r  = __builtin_amdgcn_sqrtf(d2);
                    float s  = r - tcs[a][jj];
                    s_tpl = fmaf(s, s, s_tpl);
                    float dd  = r + 0.01f;
                    float inv = __builtin_amdgcn_rcpf(dd);
                    float i2 = inv * inv;
                    float i6 = i2 * i2 * i2;
                    s_vdw = fmaf(i6, i6 - 1.f, s_vdw);
                    s_elec = fmaf(row[a].w * col[jj].w, inv, s_elec);
                }
        }
        double dt = (double)s_tpl, de = (double)s_elec, dv = (double)s_vdw;
        for (int off = 32; off; off >>= 1) {
            dt += __shfl_down(dt, off);
            de += __shfl_down(de, off);
            dv += __shfl_down(dv, off);
        }
        int wv = tid >> 6;
        if ((tid & 63) == 0) { wred[wv] = dt; wred[4 + wv] = de; wred[8 + wv] = dv; }
        __syncthreads();
        if (tid == 0) {
            pT[vb] = (wred[0] + wred[1]) + (wred[2] + wred[3]);
            pE[vb] = (wred[4] + wred[5]) + (wred[6] + wred[7]);
            pV[vb] = (wred[8] + wred[9]) + (wred[10] + wred[11]);
        }
    } else if (vb < 3072) {
        // ---------------- vq-score: 64x64 tile, 4x4/thread, K in 4 chunks of 32
        int sb = vb - 2048;
        int rt = sb >> 3, ct = sb & 7;
        int r0 = rt * 64, c0 = ct * 64;
        float* lf = (float*)smem;              // 8 KB
        float* le = (float*)(smem + 8192);     // 8 KB
        float* e2s = (float*)(smem + 16384);   // 256 B

        float e2r = 0.f;
        if (tid < 64) {
            const float* e = emb + (size_t)(c0 + tid) * D_;
            float s0 = 0.f, s1 = 0.f, s2 = 0.f, s3 = 0.f;
            for (int d = 0; d < D_; d += 4) {
                float4 v = *(const float4*)&e[d];
                s0 = fmaf(v.x, v.x, s0);
                s1 = fmaf(v.y, v.y, s1);
                s2 = fmaf(v.z, v.z, s2);
                s3 = fmaf(v.w, v.w, s3);
            }
            e2r = (s0 + s1) + (s2 + s3);
        }

        int ti = tid >> 4, tj = tid & 15;
        float acc[4][4];
#pragma unroll
        for (int a = 0; a < 4; a++)
#pragma unroll
            for (int b = 0; b < 4; b++) acc[a][b] = 0.f;

        for (int kc = 0; kc < 4; kc++) {
#pragma unroll
            for (int v = tid; v < 512; v += 256) {
                int r  = v >> 3;
                int d4 = (v & 7) << 2;
                int dsw = d4 ^ (((r >> 3) & 7) << 2);
                *(float4*)&lf[r * 32 + dsw] = *(const float4*)&enc[(size_t)(r0 + r) * D_ + kc * 32 + d4];
                *(float4*)&le[r * 32 + dsw] = *(const float4*)&emb[(size_t)(c0 + r) * D_ + kc * 32 + d4];
            }
            __syncthreads();
#pragma unroll
            for (int d4 = 0; d4 < 32; d4 += 4) {
                float4 fa[4], eb[4];
#pragma unroll
                for (int rr = 0; rr < 4; rr++) {
                    int row = ti * 4 + rr;
                    fa[rr] = *(float4*)&lf[row * 32 + (d4 ^ (((row >> 3) & 7) << 2))];
                }
#pragma unroll
                for (int cc = 0; cc < 4; cc++) {
                    int c = tj * 4 + cc;
                    eb[cc] = *(float4*)&le[c * 32 + (d4 ^ (((c >> 3) & 7) << 2))];
                }
#pragma unroll
                for (int rr = 0; rr < 4; rr++)
#pragma unroll
                    for (int cc = 0; cc < 4; cc++) {
                        acc[rr][cc] = fmaf(fa[rr].x, eb[cc].x, acc[rr][cc]);
                        acc[rr][cc] = fmaf(fa[rr].y, eb[cc].y, acc[rr][cc]);
                        acc[rr][cc] = fmaf(fa[rr].z, eb[cc].z, acc[rr][cc]);
                        acc[rr][cc] = fmaf(fa[rr].w, eb[cc].w, acc[rr][cc]);
                    }
            }
            __syncthreads();
        }

        if (tid < 64) e2s[tid] = e2r;
        __syncthreads();

        unsigned long long* red = (unsigned long long*)smem;   // 64*17*8 = 8.7 KB (lf/le dead)
#pragma unroll
        for (int rr = 0; rr < 4; rr++) {
            int r = ti * 4 + rr;
            float bs = __uint_as_float(0x7F800000u); int bidx = 0;
#pragma unroll
            for (int cc = 0; cc < 4; cc++) {
                int c = tj * 4 + cc;
                float s = e2s[c] - 2.f * acc[rr][cc];
                if (s < bs) { bs = s; bidx = c0 + c; }
            }
            unsigned ub = __float_as_uint(bs);
            ub = (ub & 0x80000000u) ? ~ub : (ub | 0x80000000u);
            red[r * 17 + tj] = ((unsigned long long)ub << 32) | (unsigned)bidx;
        }
        __syncthreads();
        if (tid < 64) {
            unsigned long long mn = red[tid * 17 + 0];
            for (int t = 1; t < 16; t++) {
                unsigned long long v = red[tid * 17 + t];
                mn = (v < mn) ? v : mn;
            }
            vqbPart[ct * 8192 + r0 + tid] = mn;
        }
        __syncthreads();
        if (tid == 0) { __threadfence(); atomicAdd(&cnts[0], 1u); }   // producer signal
    } else if (vb < 4096) {
        // ---------------- yy: tpl_scaffold
        int sb = vb - 3072;
        float4* la4 = (float4*)smem;
        float4* lb4 = (float4*)(smem + 4096);
        double* wred = (double*)(smem + 8192);
        int it = sb >> 5, jt = sb & 31;
        int i0 = it * 64, j0 = jt * 64;
        {
            int b = tid >> 6, r = tid & 63;
            const float* ap = &yg[((size_t)(b * M_ + i0 + r)) * 3];
            la4[tid] = make_float4(ap[0], ap[1], ap[2], 0.f);
            const float* bp = &yg[((size_t)(b * M_ + j0 + r)) * 3];
            lb4[tid] = make_float4(bp[0], bp[1], bp[2], 0.f);
        }
        __syncthreads();

        int tj = tid & 15, ti = tid >> 4;
        float tcs[4][4];
#pragma unroll
        for (int a = 0; a < 4; a++) {
            const float* tr = &Ts[((size_t)(i0 + ti * 4 + a)) * M_ + j0 + tj];
#pragma unroll
            for (int jj = 0; jj < 4; jj++) tcs[a][jj] = tr[jj * 16];
        }
        float s_tpl = 0.f;
#pragma unroll
        for (int b = 0; b < B_; b++) {
            float4 row[4], col[4];
#pragma unroll
            for (int a = 0; a < 4; a++) row[a] = la4[b * 64 + ti * 4 + a];
#pragma unroll
            for (int jj = 0; jj < 4; jj++) col[jj] = lb4[b * 64 + jj * 16 + tj];
#pragma unroll
            for (int jj = 0; jj < 4; jj++)
#pragma unroll
                for (int a = 0; a < 4; a++) {
                    float dx = row[a].x - col[jj].x;
                    float dy = row[a].y - col[jj].y;
                    float dz = row[a].z - col[jj].z;
                    float d2 = fmaf(dz, dz, fmaf(dy, dy, dx * dx));
                    float r  = __builtin_amdgcn_sqrtf(d2);
                    float s  = r - tcs[a][jj];
                    s_tpl = fmaf(s, s, s_tpl);
                }
        }
        double dt = (double)s_tpl;
        for (int off = 32; off; off >>= 1) dt += __shfl_down(dt, off);
        if ((tid & 63) == 0) wred[tid >> 6] = dt;
        __syncthreads();
        if (tid == 0) pyy[sb] = (wred[0] + wred[1]) + (wred[2] + wred[3]);
    } else if (vb < 5120) {
        // ---------------- chamfer (both sides); init done by k_zero
        int sub = vb - 4096;
        const float* A; const float* Bsd; unsigned* outmin;
        if (sub < 512) { A = x;  Bsd = yg; outmin = rowmin; }
        else           { A = yg; Bsd = x;  outmin = colmin; sub -= 512; }
        float4* lb = (float4*)smem;
        int rc = sub >> 4;
        int jc = sub & 15;
        int row = rc * 256 + tid;
        int b = row >> 11;
        int j0 = jc * 128;

        for (int t = tid; t < 128 * 3; t += 256) {
            int j = t / 3, c = t % 3;
            ((float*)&lb[j])[c] = Bsd[((size_t)(b * 2048 + j0 + j)) * 3 + c];
        }
        __syncthreads();

        const float* p = &A[(size_t)row * 3];
        float ax = p[0], ay = p[1], az = p[2];
        float m2 = __uint_as_float(0x7F800000u);
#pragma unroll 4
        for (int j = 0; j < 128; j++) {
            float4 pv = lb[j];
            float dx = ax - pv.x, dy = ay - pv.y, dz = az - pv.z;
            m2 = fminf(m2, fmaf(dz, dz, fmaf(dy, dy, dx * dx)));
        }
        atomicMin(&outmin[row], __float_as_uint(m2));
    } else {
        // ---------------- vqep: wait for 1024 vq blocks, then MSE over 32 rows
        int sb = vb - 5120;
        double* sred = (double*)smem;
        if (tid == 0) {
            while (__hip_atomic_load(&cnts[0], __ATOMIC_ACQUIRE, __HIP_MEMORY_SCOPE_AGENT) < 1024u)
                __builtin_amdgcn_s_sleep(8);
        }
        __syncthreads();
        int base = sb * 32;
        int wv = tid >> 6, lane = tid & 63;
        double s = 0.0;
#pragma unroll
        for (int it8 = 0; it8 < 8; it8++) {
            int w = base + wv * 8 + it8;
            unsigned long long m = vqbPart[w];
#pragma unroll
            for (int p = 1; p < 8; p++) {
                unsigned long long t = vqbPart[p * 8192 + w];
                m = (t < m) ? t : m;
            }
            int idx = (int)(m & 0xFFFFFFFFu);
            float2 fv = *(const float2*)&enc[(size_t)w * D_ + lane * 2];
            float2 ev = *(const float2*)&emb[(size_t)idx * D_ + lane * 2];
            float d0 = ev.x - fv.x, d1 = ev.y - fv.y;
            s += (double)(d0 * d0) + (double)(d1 * d1);
        }
        for (int off = 32; off; off >>= 1) s += __shfl_down(s, off);
        if (lane == 0) sred[wv] = s;
        __syncthreads();
        if (tid == 0) pvq[sb] = (sred[0] + sred[1]) + (sred[2] + sred[3]);
    }

    // ---------------- last-block final combine
    __syncthreads();
    if (tid == 0) {
        __threadfence();
        unsigned old = atomicAdd(&cnts[1], 1u);
        lastFlag = (old == NBLK - 1) ? 1u : 0u;
    }
    __syncthreads();
    if (lastFlag) {
        __threadfence();
        double* sh = (double*)smem;            // 6 x 256 doubles = 12 KB
        double sc = 0.0, sT = 0.0, sE = 0.0, sV = 0.0, sY = 0.0, sQ = 0.0;
        for (int i = tid; i < 2048; i += 256) {
            uint4 v = ((const uint4*)rowmin)[i];
            sc += (double)__builtin_amdgcn_sqrtf(__uint_as_float(v.x))
                + (double)__builtin_amdgcn_sqrtf(__uint_as_float(v.y))
                + (double)__builtin_amdgcn_sqrtf(__uint_as_float(v.z))
                + (double)__builtin_amdgcn_sqrtf(__uint_as_float(v.w));
            uint4 w = ((const uint4*)colmin)[i];
            sc += (double)__builtin_amdgcn_sqrtf(__uint_as_float(w.x))
                + (double)__builtin_amdgcn_sqrtf(__uint_as_float(w.y))
                + (double)__builtin_amdgcn_sqrtf(__uint_as_float(w.z))
                + (double)__builtin_amdgcn_sqrtf(__uint_as_float(w.w));
        }
        for (int i = tid; i < 1024; i += 256) {
            double2 a = ((const double2*)pT)[i];  sT += a.x + a.y;
            double2 b = ((const double2*)pE)[i];  sE += b.x + b.y;
            double2 c = ((const double2*)pV)[i];  sV += c.x + c.y;
            sY += pyy[i];
        }
        sQ = pvq[tid];
        sh[0 * 256 + tid] = sc; sh[1 * 256 + tid] = sT; sh[2 * 256 + tid] = sE;
        sh[3 * 256 + tid] = sV; sh[4 * 256 + tid] = sY; sh[5 * 256 + tid] = sQ;
        __syncthreads();
        for (int st = 128; st; st >>= 1) {
            if (tid < st)
#pragma unroll
                for (int q = 0; q < 6; q++) sh[q * 256 + tid] += sh[q * 256 + tid + st];
            __syncthreads();
        }
        if (tid == 0) {
            double chamfer = sh[0] / (double)(B_ * N_);
            double vq  = 1.25 * sh[5 * 256] / (double)((size_t)B_ * M_ * D_);
            double tyy = sh[4 * 256] / (double)((size_t)B_ * M_ * M_);
            double tcr = sh[1 * 256] / (double)((size_t)B_ * M_ * M2_);
            double el  = 0.1 * (sh[2 * 256] + sh[3 * 256]) / (double)B_;
            out[0] = (float)(chamfer + vq + tyy + tcr + el);
        }
    }
}

// ---------------------------------------------------------------- launch
extern "C" void kernel_launch(void* const* d_in, const int* in_sizes, int n_in,
                              void* d_out, int out_size, void* d_ws, size_t ws_size,
                              hipStream_t stream) {
    const float* x   = (const float*)d_in[0];
    const float* y   = (const float*)d_in[1];
    const float* enc = (const float*)d_in[2];
    const float* pc  = (const float*)d_in[3];
    const float* sf  = (const float*)d_in[4];
    const float* pf  = (const float*)d_in[5];
    const float* Ts  = (const float*)d_in[6];
    const float* Tc  = (const float*)d_in[7];
    const float* emb = (const float*)d_in[8];
    float* out = (float*)d_out;

    char* ws = (char*)d_ws;
    unsigned* rowmin         = (unsigned*)(ws + 0);        // 32 KB
    unsigned* colmin         = (unsigned*)(ws + 32768);    // 32 KB
    unsigned long long* vqbP = (unsigned long long*)(ws + 65536);  // 512 KB (8x8192)
    double* pT               = (double*)(ws + 589824);     // 16 KB
    double* pE               = (double*)(ws + 606208);
    double* pV               = (double*)(ws + 622592);
    double* pyy              = (double*)(ws + 638976);     // 8 KB
    double* pvq              = (double*)(ws + 647168);     // 2 KB
    unsigned* cnts           = (unsigned*)(ws + 649216);   // 8 B

    hipLaunchKernelGGL(k_zero, dim3(32), dim3(256), 0, stream, rowmin, colmin, cnts);
    hipLaunchKernelGGL(k_all, dim3(NBLK), dim3(256), 0, stream,
                       x, y, pc, enc, emb, Ts, Tc, sf, pf, vqbP,
                       rowmin, colmin, pT, pE, pV, pyy, pvq, cnts, out);
}